// Round 8
// baseline (136.644 us; speedup 1.0000x reference)
//
#include <hip/hip_runtime.h>
#include <hip/hip_fp16.h>
#include <stdint.h>

#define HH 512
#define WW 512
#define NPIX (HH*WW)
#define ALPHA_MIN_C (1.0f/255.0f)
#define ALPHA_MAX_C 0.99f
#define BLUR_C 0.3f
#define TERM_EPS 1.0e-4f
#define LOG2E 1.4426950408889634f

// ---------------- Kernel 1: partial stable-rank counts (no atomics) -----------
// rank[g] = #{ j : d[j] < d[g] or (d[j]==d[g] and j<g) }  (JAX stable argsort)
#define JSL 512
__global__ __launch_bounds__(256) void rank_kernel(const float* __restrict__ depths,
                                                   int N, int* __restrict__ partial) {
    __shared__ uint32_t sk[JSL];
    const int tid = threadIdx.x;
    const int ngb = N >> 8;                       // 32
    const int gb = blockIdx.x % ngb;
    const int jb = blockIdx.x / ngb;
    const int j0 = jb * JSL;
    for (int i = tid; i < JSL; i += 256)
        sk[i] = __float_as_uint(depths[j0 + i]);
    __syncthreads();
    const int g = gb * 256 + tid;
    const uint32_t mb = __float_as_uint(depths[g]);
    const int glim = g - j0;                      // tie j0+i < g  <=>  i < glim
    int cnt = 0;
    const uint4* sk4 = (const uint4*)sk;
#pragma unroll 8
    for (int q = 0; q < JSL / 4; ++q) {
        uint4 v = sk4[q];
        const int i4 = q * 4;
        cnt += (v.x < mb) || (v.x == mb && (i4 + 0) < glim);
        cnt += (v.y < mb) || (v.y == mb && (i4 + 1) < glim);
        cnt += (v.z < mb) || (v.z == mb && (i4 + 2) < glim);
        cnt += (v.w < mb) || (v.w == mb && (i4 + 3) < glim);
    }
    partial[jb * N + g] = cnt;
}

// ---------------- Kernel 2: prep + scatter into sorted order ------------------
// pP[pos] = (mx, my, r2, op)   pQ[pos] = (iaF, ibF|icF f16x2, rgb10, 0)
__global__ __launch_bounds__(256) void prep_kernel(
    const float* __restrict__ means, const float* __restrict__ colors,
    const float* __restrict__ ops, const float* __restrict__ scales,
    const float* __restrict__ rots, const int* __restrict__ partial, int N,
    float4* __restrict__ pP, float4* __restrict__ pQ) {
    int g = blockIdx.x * 256 + threadIdx.x;
    if (g >= N) return;
    int pos = 0;
#pragma unroll
    for (int s = 0; s < 16; ++s) pos += partial[s * N + g];
    float mx = means[2*g], my = means[2*g+1];
    float th = rots[g];
    float c = cosf(th), si = sinf(th);
    float sx = scales[2*g], sy = scales[2*g+1];
    float sx2 = sx*sx, sy2 = sy*sy;
    float A  = c*c*sx2 + si*si*sy2;
    float Cc = si*si*sx2 + c*c*sy2;
    float B  = c*si*(sx2 - sy2);
    float det = A*Cc - B*B;
    float A2 = A + BLUR_C, C2 = Cc + BLUR_C;
    float det2 = A2*C2 - B*B;
    float op = ops[g] * sqrtf(fmaxf(det/det2, 0.0f));
    float invd = 1.0f/det2;
    float ia = C2*invd, ib = -B*invd, ic = A2*invd;       // Sigma^-1
    float iaF = -0.5f*LOG2E*ia, icF = -0.5f*LOG2E*ic, ibF = -LOG2E*ib;
    float mid = 0.5f*(A2+C2);
    float lam = mid + sqrtf(fmaxf(mid*mid - det2, 0.0f));
    float r2;
    if (op < ALPHA_MIN_C) {
        r2 = -1.0f;
    } else {
        float t = __logf(op * 255.0f);
        r2 = fmaxf(2.0f * lam * t, 0.0f) * 1.0001f + 0.25f;
    }
    __half2 h2 = __floats2half2_rn(ibF, icF);
    unsigned ibic; __builtin_memcpy(&ibic, &h2, 4);
    unsigned r10 = __float2uint_rn(fminf(colors[3*g  ], 1.0f) * 1023.0f);
    unsigned g10 = __float2uint_rn(fminf(colors[3*g+1], 1.0f) * 1023.0f);
    unsigned b10 = __float2uint_rn(fminf(colors[3*g+2], 1.0f) * 1023.0f);
    unsigned rgb = r10 | (g10 << 10) | (b10 << 20);
    pP[pos] = make_float4(mx, my, r2, op);
    pQ[pos] = make_float4(iaF, __uint_as_float(ibic), __uint_as_float(rgb), 0.0f);
}

// ---------------- Kernel 3: depth-segmented blend -----------------------------
// 8 segments x 1024 tiles = 8192 one-wave (64-thread) blocks. Each block
// renders its tile against gaussians [seg*1024, seg*1024+1024) from T=1 and
// writes (A_rgb, T) per pixel as 4xf16. Compositing is associative, so a
// later pass folds segments in order. 4 px/lane (rows y, y+4, y+8, y+12):
// decode + dx-terms amortized. One wave per block -> no barriers at all.
#define NSEG 8
#define SEGG 1024
#define CHK  128
#define NCHK (SEGG/CHK)   // 8

__device__ __forceinline__ uint2 packAT(float r, float g, float b, float t) {
    __half2 hrg = __floats2half2_rn(r, g);
    __half2 hbt = __floats2half2_rn(b, t);
    uint2 u;
    __builtin_memcpy(&u.x, &hrg, 4);
    __builtin_memcpy(&u.y, &hbt, 4);
    return u;
}

__global__ __launch_bounds__(64) void seg_blend_kernel(
    const float4* __restrict__ pP, const float4* __restrict__ pQ,
    uint2* __restrict__ segbuf) {
    // record: 8 floats (32B): [mx, my, iaF, ib|ic, op, rgb, pad, pad]
    __shared__ __align__(16) float sG[2][CHK*8];
    const int lane = threadIdx.x;                 // 0..63
    const int tile = blockIdx.x & 1023;
    const int seg  = blockIdx.x >> 10;            // 0..7
    const int tX = tile & 31, tY = tile >> 5;
    const int px = tX*16 + (lane & 15);
    const int py = tY*16 + (lane >> 4);           // rows 0..3 (+4k below)
    const float fx = px + 0.5f, fy = py + 0.5f;
    const float x0 = tX*16 + 0.5f, x1 = x0 + 15.0f;
    const float y0 = tY*16 + 0.5f, y1 = y0 + 15.0f;
    const uint64_t lm = (1ull << lane) - 1ull;
    float T0=1.f,T1=1.f,T2=1.f,T3=1.f;
    float aR0=0.f,aG0=0.f,aB0=0.f;
    float aR1=0.f,aG1=0.f,aB1=0.f;
    float aR2=0.f,aG2=0.f,aB2=0.f;
    float aR3=0.f,aG3=0.f,aB3=0.f;
    const int gb = seg * SEGG;

    float4 a0 = pP[gb+lane],    q0 = pQ[gb+lane];
    float4 a1 = pP[gb+64+lane], q1 = pQ[gb+64+lane];
    int cntA = 0, cntB = 0;
    // stage chunk 0 -> buf 0
    {
        float nx = fminf(fmaxf(a0.x,x0),x1)-a0.x, ny = fminf(fmaxf(a0.y,y0),y1)-a0.y;
        bool f0 = (nx*nx + ny*ny) <= a0.z;
        nx = fminf(fmaxf(a1.x,x0),x1)-a1.x; ny = fminf(fmaxf(a1.y,y0),y1)-a1.y;
        bool f1 = (nx*nx + ny*ny) <= a1.z;
        uint64_t m0 = __ballot(f0);
        if (f0) { float* rec = &sG[0][__popcll(m0 & lm)*8];
                  *(float4*)rec = make_float4(a0.x,a0.y,q0.x,q0.y);
                  *(float2*)(rec+4) = make_float2(a0.w,q0.z); }
        int c0 = (int)__popcll(m0);
        uint64_t m1 = __ballot(f1);
        if (f1) { float* rec = &sG[0][(c0 + __popcll(m1 & lm))*8];
                  *(float4*)rec = make_float4(a1.x,a1.y,q1.x,q1.y);
                  *(float2*)(rec+4) = make_float2(a1.w,q1.z); }
        cntA = c0 + (int)__popcll(m1);
    }
    {   const int g = gb + CHK + lane;
        a0 = pP[g]; q0 = pQ[g]; a1 = pP[g+64]; q1 = pQ[g+64]; }

    int cur = 0;
    for (int k = 0; k < NCHK; ++k) {
        const int nxt = cur ^ 1;
        if (k + 1 < NCHK) {
            // stage chunk k+1 into buf[nxt] (single wave: program order + lgkmcnt
            // give all the fencing we need; buf[nxt] reads finished last iter)
            float nx = fminf(fmaxf(a0.x,x0),x1)-a0.x, ny = fminf(fmaxf(a0.y,y0),y1)-a0.y;
            bool f0 = (nx*nx + ny*ny) <= a0.z;
            nx = fminf(fmaxf(a1.x,x0),x1)-a1.x; ny = fminf(fmaxf(a1.y,y0),y1)-a1.y;
            bool f1 = (nx*nx + ny*ny) <= a1.z;
            uint64_t m0 = __ballot(f0);
            if (f0) { float* rec = &sG[nxt][__popcll(m0 & lm)*8];
                      *(float4*)rec = make_float4(a0.x,a0.y,q0.x,q0.y);
                      *(float2*)(rec+4) = make_float2(a0.w,q0.z); }
            int c0 = (int)__popcll(m0);
            uint64_t m1 = __ballot(f1);
            if (f1) { float* rec = &sG[nxt][(c0 + __popcll(m1 & lm))*8];
                      *(float4*)rec = make_float4(a1.x,a1.y,q1.x,q1.y);
                      *(float2*)(rec+4) = make_float2(a1.w,q1.z); }
            const int cn = c0 + (int)__popcll(m1);
            if (nxt == 0) cntA = cn; else cntB = cn;
            if (k + 2 < NCHK) {
                const int g = gb + (k+2)*CHK + lane;
                a0 = pP[g]; q0 = pQ[g]; a1 = pP[g+64]; q1 = pQ[g+64];
            }
        }
        const int cnt = (cur == 0) ? cntA : cntB;
        const float* segp = sG[cur];
        for (int i = 0; i < cnt; ++i) {
            const float4 r0 = *(const float4*)(segp + i*8);      // b128
            const float2 r1 = *(const float2*)(segp + i*8 + 4);  // b64
            float dx = fx - r0.x;
            float dy = fy - r0.y;
            unsigned hh = __float_as_uint(r0.w);
            __half2 h2; __builtin_memcpy(&h2, &hh, 4);
            float ibv = __half2float(h2.x);
            float icv = __half2float(h2.y);
            float bse = r0.z * (dx*dx);              // iaF*dx^2 (shared by 4 px)
            float pb  = ibv * dx;                    // ibF*dx   (shared by 4 px)
            float d1 = dy + 4.0f, d2 = dy + 8.0f, d3 = dy + 12.0f;
            float p0 = fmaf(icv, dy*dy, fmaf(pb, dy, bse));
            float p1 = fmaf(icv, d1*d1, fmaf(pb, d1, bse));
            float p2 = fmaf(icv, d2*d2, fmaf(pb, d2, bse));
            float p3 = fmaf(icv, d3*d3, fmaf(pb, d3, bse));
            float al0 = fminf(ALPHA_MAX_C, r1.x * exp2f(p0));
            float al1 = fminf(ALPHA_MAX_C, r1.x * exp2f(p1));
            float al2 = fminf(ALPHA_MAX_C, r1.x * exp2f(p2));
            float al3 = fminf(ALPHA_MAX_C, r1.x * exp2f(p3));
            al0 = (al0 >= ALPHA_MIN_C) ? al0 : 0.0f;
            al1 = (al1 >= ALPHA_MIN_C) ? al1 : 0.0f;
            al2 = (al2 >= ALPHA_MIN_C) ? al2 : 0.0f;
            al3 = (al3 >= ALPHA_MIN_C) ? al3 : 0.0f;
            if (__any((al0 > 0.f) | (al1 > 0.f) | (al2 > 0.f) | (al3 > 0.f))) {
                unsigned rgb = __float_as_uint(r1.y);
                float cr = (float)(rgb & 1023u)         * (1.0f/1023.0f);
                float cg = (float)((rgb >> 10) & 1023u) * (1.0f/1023.0f);
                float cb = (float)((rgb >> 20) & 1023u) * (1.0f/1023.0f);
                float s0 = al0*T0, s1 = al1*T1, s2 = al2*T2, s3 = al3*T3;
                aR0 = fmaf(cr,s0,aR0); aG0 = fmaf(cg,s0,aG0); aB0 = fmaf(cb,s0,aB0);
                aR1 = fmaf(cr,s1,aR1); aG1 = fmaf(cg,s1,aG1); aB1 = fmaf(cb,s1,aB1);
                aR2 = fmaf(cr,s2,aR2); aG2 = fmaf(cg,s2,aG2); aB2 = fmaf(cb,s2,aB2);
                aR3 = fmaf(cr,s3,aR3); aG3 = fmaf(cg,s3,aG3); aB3 = fmaf(cb,s3,aB3);
                T0 = fmaf(-al0,T0,T0); T1 = fmaf(-al1,T1,T1);
                T2 = fmaf(-al2,T2,T2); T3 = fmaf(-al3,T3,T3);
            }
        }
        // local early exit: remaining contribution of this segment < eps
        if (__all((T0 < TERM_EPS) & (T1 < TERM_EPS) &
                  (T2 < TERM_EPS) & (T3 < TERM_EPS))) break;
        cur = nxt;
    }
    const int pix0 = py*WW + px;
    uint2* sb = segbuf + seg * NPIX;
    sb[pix0        ] = packAT(aR0, aG0, aB0, T0);
    sb[pix0 +  4*WW] = packAT(aR1, aG1, aB1, T1);
    sb[pix0 +  8*WW] = packAT(aR2, aG2, aB2, T2);
    sb[pix0 + 12*WW] = packAT(aR3, aG3, aB3, T3);
}

// ---------------- Kernel 4: composite segments front-to-back ------------------
__global__ __launch_bounds__(256) void composite_kernel(
    const uint2* __restrict__ segbuf, const float* __restrict__ bg,
    float* __restrict__ out) {
    const int pix = blockIdx.x * 256 + threadIdx.x;
    float R = 0.f, G = 0.f, B = 0.f, T = 1.f;
#pragma unroll
    for (int s = 0; s < NSEG; ++s) {
        uint2 v = segbuf[s * NPIX + pix];
        __half2 hrg, hbt;
        __builtin_memcpy(&hrg, &v.x, 4);
        __builtin_memcpy(&hbt, &v.y, 4);
        R = fmaf(T, __half2float(hrg.x), R);
        G = fmaf(T, __half2float(hrg.y), G);
        B = fmaf(T, __half2float(hbt.x), B);
        T *= __half2float(hbt.y);
    }
    out[pix]          = R + bg[0]*T;
    out[pix +   NPIX] = G + bg[1]*T;
    out[pix + 2*NPIX] = B + bg[2]*T;
}

extern "C" void kernel_launch(void* const* d_in, const int* in_sizes, int n_in,
                              void* d_out, int out_size, void* d_ws, size_t ws_size,
                              hipStream_t stream) {
    const float* means   = (const float*)d_in[0];
    const float* colors  = (const float*)d_in[1];
    const float* ops     = (const float*)d_in[2];
    const float* scales  = (const float*)d_in[3];
    const float* rots    = (const float*)d_in[4];
    const float* depths  = (const float*)d_in[5];
    const float* bg      = (const float*)d_in[6];
    const int N = in_sizes[0] / 2;           // 8192

    char* ws = (char*)d_ws;
    float4* pP    = (float4*)(ws);                        // N*16 B
    float4* pQ    = (float4*)(ws + (size_t)N*16);         // N*16 B
    int*    part  = (int*)  (ws + (size_t)N*32);          // 16*N*4 B
    uint2*  segb  = (uint2*)(ws + (size_t)N*32 + (size_t)16*N*4);  // 16 MB

    const int ngb = N / 256;                 // 32
    const int njb = N / JSL;                 // 16
    rank_kernel<<<dim3(ngb*njb), dim3(256), 0, stream>>>(depths, N, part);
    prep_kernel<<<dim3((N+255)/256), dim3(256), 0, stream>>>(
        means, colors, ops, scales, rots, part, N, pP, pQ);
    seg_blend_kernel<<<dim3(NSEG*1024), dim3(64), 0, stream>>>(pP, pQ, segb);
    composite_kernel<<<dim3(NPIX/256), dim3(256), 0, stream>>>(
        segb, bg, (float*)d_out);
}

// Round 11
// 133.385 us; speedup vs baseline: 1.0244x; 1.0244x over previous
//
#include <hip/hip_runtime.h>
#include <hip/hip_fp16.h>
#include <stdint.h>

#define HH 512
#define WW 512
#define NPIX (HH*WW)
#define ALPHA_MIN_C (1.0f/255.0f)
#define ALPHA_MAX_C 0.99f
#define BLUR_C 0.3f
#define TERM_EPS 1.0e-4f
#define LOG2E 1.4426950408889634f

// ---------------- Kernel 1: partial stable-rank counts (no atomics) -----------
// rank[g] = #{ j : d[j] < d[g] or (d[j]==d[g] and j<g) }  (JAX stable argsort)
#define JSL 512
__global__ __launch_bounds__(256) void rank_kernel(const float* __restrict__ depths,
                                                   int N, int* __restrict__ partial) {
    __shared__ uint32_t sk[JSL];
    const int tid = threadIdx.x;
    const int ngb = N >> 8;                       // 32
    const int gb = blockIdx.x % ngb;
    const int jb = blockIdx.x / ngb;
    const int j0 = jb * JSL;
    for (int i = tid; i < JSL; i += 256)
        sk[i] = __float_as_uint(depths[j0 + i]);
    __syncthreads();
    const int g = gb * 256 + tid;
    const uint32_t mb = __float_as_uint(depths[g]);
    const int glim = g - j0;                      // tie j0+i < g  <=>  i < glim
    int cnt = 0;
    const uint4* sk4 = (const uint4*)sk;
#pragma unroll 8
    for (int q = 0; q < JSL / 4; ++q) {
        uint4 v = sk4[q];
        const int i4 = q * 4;
        cnt += (v.x < mb) || (v.x == mb && (i4 + 0) < glim);
        cnt += (v.y < mb) || (v.y == mb && (i4 + 1) < glim);
        cnt += (v.z < mb) || (v.z == mb && (i4 + 2) < glim);
        cnt += (v.w < mb) || (v.w == mb && (i4 + 3) < glim);
    }
    partial[jb * N + g] = cnt;
}

// ---------------- Kernel 2: prep + scatter into sorted order ------------------
// pP[pos] = (mx, my, bx, by)   pQ[pos] = (iaF, ibF|icF f16x2, rgb10, lop)
// AABB: alpha >= 1/255 requires |dx| <= bx AND |dy| <= by  (exact marginal
// bound: min_dy q = dx^2/Sxx), bx = sqrt(2 ln(255 op) Sxx), by likewise.
// alpha = min(.99, exp2(iaF dx^2 + icF dy^2 + ibF dx dy + lop)), lop = log2(op)
__global__ __launch_bounds__(256) void prep_kernel(
    const float* __restrict__ means, const float* __restrict__ colors,
    const float* __restrict__ ops, const float* __restrict__ scales,
    const float* __restrict__ rots, const int* __restrict__ partial, int N,
    float4* __restrict__ pP, float4* __restrict__ pQ) {
    int g = blockIdx.x * 256 + threadIdx.x;
    if (g >= N) return;
    int pos = 0;
#pragma unroll
    for (int s = 0; s < 16; ++s) pos += partial[s * N + g];
    float mx = means[2*g], my = means[2*g+1];
    float th = rots[g];
    float c = cosf(th), si = sinf(th);
    float sx = scales[2*g], sy = scales[2*g+1];
    float sx2 = sx*sx, sy2 = sy*sy;
    float A  = c*c*sx2 + si*si*sy2;
    float Cc = si*si*sx2 + c*c*sy2;
    float B  = c*si*(sx2 - sy2);
    float det = A*Cc - B*B;
    float A2 = A + BLUR_C, C2 = Cc + BLUR_C;      // dilated Sxx, Syy
    float det2 = A2*C2 - B*B;
    float op = ops[g] * sqrtf(fmaxf(det/det2, 0.0f));
    float invd = 1.0f/det2;
    float ia = C2*invd, ib = -B*invd, ic = A2*invd;       // Sigma^-1
    float iaF = -0.5f*LOG2E*ia, icF = -0.5f*LOG2E*ic, ibF = -LOG2E*ib;
    float bx, by, lop;
    if (op < ALPHA_MIN_C) {
        bx = -1.0f; by = -1.0f; lop = -128.0f;
    } else {
        float t = __logf(op * 255.0f);                    // ln(op/ALPHA_MIN) >= 0
        bx = sqrtf(fmaxf(2.0f * t * A2, 0.0f)) * 1.0001f + 0.1f;
        by = sqrtf(fmaxf(2.0f * t * C2, 0.0f)) * 1.0001f + 0.1f;
        lop = __log2f(op);
    }
    __half2 h2 = __floats2half2_rn(ibF, icF);
    unsigned ibic; __builtin_memcpy(&ibic, &h2, 4);
    unsigned r10 = __float2uint_rn(fminf(colors[3*g  ], 1.0f) * 1023.0f);
    unsigned g10 = __float2uint_rn(fminf(colors[3*g+1], 1.0f) * 1023.0f);
    unsigned b10 = __float2uint_rn(fminf(colors[3*g+2], 1.0f) * 1023.0f);
    unsigned rgb = r10 | (g10 << 10) | (b10 << 20);
    pP[pos] = make_float4(mx, my, bx, by);
    pQ[pos] = make_float4(iaF, __uint_as_float(ibic), __uint_as_float(rgb), lop);
}

// ---------------- Kernel 3: depth-segmented blend -----------------------------
// 8 segments x 1024 tiles = 8192 one-wave (64-thread) blocks; 4 px/lane
// (rows y, y+4, y+8, y+12). Segment results (A_rgb, T) packed 4xf16 to segbuf;
// compositing is associative so a later pass folds segments in depth order.
#define NSEG 8
#define SEGG 1024
#define CHK  128
#define NCHK (SEGG/CHK)   // 8

__device__ __forceinline__ uint2 packAT(float r, float g, float b, float t) {
    __half2 hrg = __floats2half2_rn(r, g);
    __half2 hbt = __floats2half2_rn(b, t);
    uint2 u;
    __builtin_memcpy(&u.x, &hrg, 4);
    __builtin_memcpy(&u.y, &hbt, 4);
    return u;
}

__global__ __launch_bounds__(64) void seg_blend_kernel(
    const float4* __restrict__ pP, const float4* __restrict__ pQ,
    uint2* __restrict__ segbuf) {
    // record: 8 floats (32B): [mx, my, iaF, ib|ic, lop, rgb, pad, pad]
    __shared__ __align__(16) float sG[2][CHK*8];
    const int lane = threadIdx.x;                 // 0..63
    const int tile = blockIdx.x & 1023;
    const int seg  = blockIdx.x >> 10;            // 0..7
    const int tX = tile & 31, tY = tile >> 5;
    const int px = tX*16 + (lane & 15);
    const int py = tY*16 + (lane >> 4);           // rows 0..3 (+4k below)
    const float fx = px + 0.5f, fy = py + 0.5f;
    const float x0 = tX*16 + 0.5f, x1 = x0 + 15.0f;
    const float y0 = tY*16 + 0.5f, y1 = y0 + 15.0f;
    const uint64_t lm = (1ull << lane) - 1ull;
    float T0=1.f,T1=1.f,T2=1.f,T3=1.f;
    float aR0=0.f,aG0=0.f,aB0=0.f;
    float aR1=0.f,aG1=0.f,aB1=0.f;
    float aR2=0.f,aG2=0.f,aB2=0.f;
    float aR3=0.f,aG3=0.f,aB3=0.f;
    const int gb = seg * SEGG;

    float4 a0 = pP[gb+lane],    q0 = pQ[gb+lane];
    float4 a1 = pP[gb+64+lane], q1 = pQ[gb+64+lane];
    int cntA = 0, cntB = 0;
    // stage chunk 0 -> buf 0
    {
        float nx = fabsf(fminf(fmaxf(a0.x,x0),x1)-a0.x);
        float ny = fabsf(fminf(fmaxf(a0.y,y0),y1)-a0.y);
        bool f0 = (nx <= a0.z) & (ny <= a0.w);
        nx = fabsf(fminf(fmaxf(a1.x,x0),x1)-a1.x);
        ny = fabsf(fminf(fmaxf(a1.y,y0),y1)-a1.y);
        bool f1 = (nx <= a1.z) & (ny <= a1.w);
        uint64_t m0 = __ballot(f0);
        if (f0) { float* rec = &sG[0][__popcll(m0 & lm)*8];
                  *(float4*)rec = make_float4(a0.x,a0.y,q0.x,q0.y);
                  *(float2*)(rec+4) = make_float2(q0.w,q0.z); }
        int c0 = (int)__popcll(m0);
        uint64_t m1 = __ballot(f1);
        if (f1) { float* rec = &sG[0][(c0 + __popcll(m1 & lm))*8];
                  *(float4*)rec = make_float4(a1.x,a1.y,q1.x,q1.y);
                  *(float2*)(rec+4) = make_float2(q1.w,q1.z); }
        cntA = c0 + (int)__popcll(m1);
    }
    {   const int g = gb + CHK + lane;
        a0 = pP[g]; q0 = pQ[g]; a1 = pP[g+64]; q1 = pQ[g+64]; }

    int cur = 0;
    for (int k = 0; k < NCHK; ++k) {
        const int nxt = cur ^ 1;
        if (k + 1 < NCHK) {
            // stage chunk k+1 into buf[nxt] (single wave: program order + lgkmcnt
            // give all the fencing we need; buf[nxt] reads finished last iter)
            float nx = fabsf(fminf(fmaxf(a0.x,x0),x1)-a0.x);
            float ny = fabsf(fminf(fmaxf(a0.y,y0),y1)-a0.y);
            bool f0 = (nx <= a0.z) & (ny <= a0.w);
            nx = fabsf(fminf(fmaxf(a1.x,x0),x1)-a1.x);
            ny = fabsf(fminf(fmaxf(a1.y,y0),y1)-a1.y);
            bool f1 = (nx <= a1.z) & (ny <= a1.w);
            uint64_t m0 = __ballot(f0);
            if (f0) { float* rec = &sG[nxt][__popcll(m0 & lm)*8];
                      *(float4*)rec = make_float4(a0.x,a0.y,q0.x,q0.y);
                      *(float2*)(rec+4) = make_float2(q0.w,q0.z); }
            int c0 = (int)__popcll(m0);
            uint64_t m1 = __ballot(f1);
            if (f1) { float* rec = &sG[nxt][(c0 + __popcll(m1 & lm))*8];
                      *(float4*)rec = make_float4(a1.x,a1.y,q1.x,q1.y);
                      *(float2*)(rec+4) = make_float2(q1.w,q1.z); }
            const int cn = c0 + (int)__popcll(m1);
            if (nxt == 0) cntA = cn; else cntB = cn;
            if (k + 2 < NCHK) {
                const int g = gb + (k+2)*CHK + lane;
                a0 = pP[g]; q0 = pQ[g]; a1 = pP[g+64]; q1 = pQ[g+64];
            }
        }
        const int cnt = (cur == 0) ? cntA : cntB;
        const float* segp = sG[cur];
#pragma unroll 2
        for (int i = 0; i < cnt; ++i) {
            const float4 r0 = *(const float4*)(segp + i*8);      // b128
            const float2 r1 = *(const float2*)(segp + i*8 + 4);  // b64
            float dx = fx - r0.x;
            float dy = fy - r0.y;
            unsigned hh = __float_as_uint(r0.w);
            __half2 h2; __builtin_memcpy(&h2, &hh, 4);
            float ibv = __half2float(h2.x);
            float icv = __half2float(h2.y);
            // direct per-row evaluation (round-8-proven math, lop folded in)
            float bse = fmaf(r0.z, dx*dx, r1.x);     // iaF*dx^2 + lop
            float pb  = ibv * dx;                    // ibF*dx (shared by 4 rows)
            float d1 = dy + 4.0f, d2 = dy + 8.0f, d3 = dy + 12.0f;
            float p0 = fmaf(icv, dy*dy, fmaf(pb, dy, bse));
            float p1 = fmaf(icv, d1*d1, fmaf(pb, d1, bse));
            float p2 = fmaf(icv, d2*d2, fmaf(pb, d2, bse));
            float p3 = fmaf(icv, d3*d3, fmaf(pb, d3, bse));
            float al0 = fminf(ALPHA_MAX_C, exp2f(p0));
            float al1 = fminf(ALPHA_MAX_C, exp2f(p1));
            float al2 = fminf(ALPHA_MAX_C, exp2f(p2));
            float al3 = fminf(ALPHA_MAX_C, exp2f(p3));
            al0 = (al0 >= ALPHA_MIN_C) ? al0 : 0.0f;
            al1 = (al1 >= ALPHA_MIN_C) ? al1 : 0.0f;
            al2 = (al2 >= ALPHA_MIN_C) ? al2 : 0.0f;
            al3 = (al3 >= ALPHA_MIN_C) ? al3 : 0.0f;
            if (__any((al0 > 0.f) | (al1 > 0.f) | (al2 > 0.f) | (al3 > 0.f))) {
                unsigned rgb = __float_as_uint(r1.y);
                float cr = (float)(rgb & 1023u)         * (1.0f/1023.0f);
                float cg = (float)((rgb >> 10) & 1023u) * (1.0f/1023.0f);
                float cb = (float)((rgb >> 20) & 1023u) * (1.0f/1023.0f);
                float s0 = al0*T0, s1 = al1*T1, s2 = al2*T2, s3 = al3*T3;
                aR0 = fmaf(cr,s0,aR0); aG0 = fmaf(cg,s0,aG0); aB0 = fmaf(cb,s0,aB0);
                aR1 = fmaf(cr,s1,aR1); aG1 = fmaf(cg,s1,aG1); aB1 = fmaf(cb,s1,aB1);
                aR2 = fmaf(cr,s2,aR2); aG2 = fmaf(cg,s2,aG2); aB2 = fmaf(cb,s2,aB2);
                aR3 = fmaf(cr,s3,aR3); aG3 = fmaf(cg,s3,aG3); aB3 = fmaf(cb,s3,aB3);
                T0 = fmaf(-al0,T0,T0); T1 = fmaf(-al1,T1,T1);
                T2 = fmaf(-al2,T2,T2); T3 = fmaf(-al3,T3,T3);
            }
        }
        // local early exit: remaining contribution of this segment < eps
        if (__all((T0 < TERM_EPS) & (T1 < TERM_EPS) &
                  (T2 < TERM_EPS) & (T3 < TERM_EPS))) break;
        cur = nxt;
    }
    const int pix0 = py*WW + px;
    uint2* sb = segbuf + seg * NPIX;
    sb[pix0        ] = packAT(aR0, aG0, aB0, T0);
    sb[pix0 +  4*WW] = packAT(aR1, aG1, aB1, T1);
    sb[pix0 +  8*WW] = packAT(aR2, aG2, aB2, T2);
    sb[pix0 + 12*WW] = packAT(aR3, aG3, aB3, T3);
}

// ---------------- Kernel 4: composite segments front-to-back ------------------
__global__ __launch_bounds__(256) void composite_kernel(
    const uint2* __restrict__ segbuf, const float* __restrict__ bg,
    float* __restrict__ out) {
    const int pix = blockIdx.x * 256 + threadIdx.x;
    float R = 0.f, G = 0.f, B = 0.f, T = 1.f;
#pragma unroll
    for (int s = 0; s < NSEG; ++s) {
        uint2 v = segbuf[s * NPIX + pix];
        __half2 hrg, hbt;
        __builtin_memcpy(&hrg, &v.x, 4);
        __builtin_memcpy(&hbt, &v.y, 4);
        R = fmaf(T, __half2float(hrg.x), R);
        G = fmaf(T, __half2float(hrg.y), G);
        B = fmaf(T, __half2float(hbt.x), B);
        T *= __half2float(hbt.y);
    }
    out[pix]          = R + bg[0]*T;
    out[pix +   NPIX] = G + bg[1]*T;
    out[pix + 2*NPIX] = B + bg[2]*T;
}

extern "C" void kernel_launch(void* const* d_in, const int* in_sizes, int n_in,
                              void* d_out, int out_size, void* d_ws, size_t ws_size,
                              hipStream_t stream) {
    const float* means   = (const float*)d_in[0];
    const float* colors  = (const float*)d_in[1];
    const float* ops     = (const float*)d_in[2];
    const float* scales  = (const float*)d_in[3];
    const float* rots    = (const float*)d_in[4];
    const float* depths  = (const float*)d_in[5];
    const float* bg      = (const float*)d_in[6];
    const int N = in_sizes[0] / 2;           // 8192

    char* ws = (char*)d_ws;
    float4* pP    = (float4*)(ws);                        // N*16 B
    float4* pQ    = (float4*)(ws + (size_t)N*16);         // N*16 B
    int*    part  = (int*)  (ws + (size_t)N*32);          // 16*N*4 B
    uint2*  segb  = (uint2*)(ws + (size_t)N*32 + (size_t)16*N*4);  // 16 MB

    const int ngb = N / 256;                 // 32
    const int njb = N / JSL;                 // 16
    rank_kernel<<<dim3(ngb*njb), dim3(256), 0, stream>>>(depths, N, part);
    prep_kernel<<<dim3((N+255)/256), dim3(256), 0, stream>>>(
        means, colors, ops, scales, rots, part, N, pP, pQ);
    seg_blend_kernel<<<dim3(NSEG*1024), dim3(64), 0, stream>>>(pP, pQ, segb);
    composite_kernel<<<dim3(NPIX/256), dim3(256), 0, stream>>>(
        segb, bg, (float*)d_out);
}

// Round 12
// 132.474 us; speedup vs baseline: 1.0315x; 1.0069x over previous
//
#include <hip/hip_runtime.h>
#include <hip/hip_fp16.h>
#include <stdint.h>

#define HH 512
#define WW 512
#define NPIX (HH*WW)
#define ALPHA_MIN_C (1.0f/255.0f)
#define ALPHA_MAX_C 0.99f
#define BLUR_C 0.3f
#define TERM_EPS 1.0e-4f
#define LOG2E 1.4426950408889634f

// ---------------- Kernel 1: partial stable-rank counts (no atomics) -----------
// rank[g] = #{ j : d[j] < d[g] or (d[j]==d[g] and j<g) }  (JAX stable argsort)
#define JSL 512
__global__ __launch_bounds__(256) void rank_kernel(const float* __restrict__ depths,
                                                   int N, int* __restrict__ partial) {
    __shared__ uint32_t sk[JSL];
    const int tid = threadIdx.x;
    const int ngb = N >> 8;                       // 32
    const int gb = blockIdx.x % ngb;
    const int jb = blockIdx.x / ngb;
    const int j0 = jb * JSL;
    for (int i = tid; i < JSL; i += 256)
        sk[i] = __float_as_uint(depths[j0 + i]);
    __syncthreads();
    const int g = gb * 256 + tid;
    const uint32_t mb = __float_as_uint(depths[g]);
    const int glim = g - j0;                      // tie j0+i < g  <=>  i < glim
    int cnt = 0;
    const uint4* sk4 = (const uint4*)sk;
#pragma unroll 8
    for (int q = 0; q < JSL / 4; ++q) {
        uint4 v = sk4[q];
        const int i4 = q * 4;
        cnt += (v.x < mb) || (v.x == mb && (i4 + 0) < glim);
        cnt += (v.y < mb) || (v.y == mb && (i4 + 1) < glim);
        cnt += (v.z < mb) || (v.z == mb && (i4 + 2) < glim);
        cnt += (v.w < mb) || (v.w == mb && (i4 + 3) < glim);
    }
    partial[jb * N + g] = cnt;
}

// ---------------- Kernel 2: prep + scatter into sorted order ------------------
// pP[pos] = (mx, my, bx, by)   pQ[pos] = (iaF, ibF|icF f16x2, lop, cr|cg f16x2)
// pC[pos] = cb (f32)
// AABB: alpha >= 1/255 requires |dx| <= bx AND |dy| <= by  (exact marginal
// bound: min_dy q = dx^2/Sxx), bx = sqrt(2 ln(255 op) Sxx), by likewise.
// alpha = min(.99, exp2(iaF dx^2 + icF dy^2 + ibF dx dy + lop)), lop = log2(op)
__global__ __launch_bounds__(256) void prep_kernel(
    const float* __restrict__ means, const float* __restrict__ colors,
    const float* __restrict__ ops, const float* __restrict__ scales,
    const float* __restrict__ rots, const int* __restrict__ partial, int N,
    float4* __restrict__ pP, float4* __restrict__ pQ, float* __restrict__ pC) {
    int g = blockIdx.x * 256 + threadIdx.x;
    if (g >= N) return;
    int pos = 0;
#pragma unroll
    for (int s = 0; s < 16; ++s) pos += partial[s * N + g];
    float mx = means[2*g], my = means[2*g+1];
    float th = rots[g];
    float c = cosf(th), si = sinf(th);
    float sx = scales[2*g], sy = scales[2*g+1];
    float sx2 = sx*sx, sy2 = sy*sy;
    float A  = c*c*sx2 + si*si*sy2;
    float Cc = si*si*sx2 + c*c*sy2;
    float B  = c*si*(sx2 - sy2);
    float det = A*Cc - B*B;
    float A2 = A + BLUR_C, C2 = Cc + BLUR_C;      // dilated Sxx, Syy
    float det2 = A2*C2 - B*B;
    float op = ops[g] * sqrtf(fmaxf(det/det2, 0.0f));
    float invd = 1.0f/det2;
    float ia = C2*invd, ib = -B*invd, ic = A2*invd;       // Sigma^-1
    float iaF = -0.5f*LOG2E*ia, icF = -0.5f*LOG2E*ic, ibF = -LOG2E*ib;
    float bx, by, lop;
    if (op < ALPHA_MIN_C) {
        bx = -1.0f; by = -1.0f; lop = -128.0f;
    } else {
        float t = __logf(op * 255.0f);                    // ln(op/ALPHA_MIN) >= 0
        bx = sqrtf(fmaxf(2.0f * t * A2, 0.0f)) * 1.0001f + 0.1f;
        by = sqrtf(fmaxf(2.0f * t * C2, 0.0f)) * 1.0001f + 0.1f;
        lop = __log2f(op);
    }
    __half2 h2 = __floats2half2_rn(ibF, icF);
    unsigned ibic; __builtin_memcpy(&ibic, &h2, 4);
    __half2 cc = __floats2half2_rn(colors[3*g], colors[3*g+1]);
    unsigned crcg; __builtin_memcpy(&crcg, &cc, 4);
    pP[pos] = make_float4(mx, my, bx, by);
    pQ[pos] = make_float4(iaF, __uint_as_float(ibic), lop, __uint_as_float(crcg));
    pC[pos] = colors[3*g+2];
}

// ---------------- Kernel 3: depth-segmented blend -----------------------------
// 4 segpairs x 1024 tiles = 4096 blocks x 128 threads (2 waves). Wave w of
// block b independently renders segment (b>>10)*2+w of tile b&1023 with its
// own private LDS double-buffer -> zero barriers, 2 waves/block residency.
// 4 px/lane (rows y, y+4, y+8, y+12). Segment (A_rgb, T) packed 4xf16 to
// segbuf; compositing is associative so a later pass folds segments in order.
#define NSEG 8
#define SEGG 1024
#define CHK  128
#define NCHK (SEGG/CHK)   // 8

__device__ __forceinline__ uint2 packAT(float r, float g, float b, float t) {
    __half2 hrg = __floats2half2_rn(r, g);
    __half2 hbt = __floats2half2_rn(b, t);
    uint2 u;
    __builtin_memcpy(&u.x, &hrg, 4);
    __builtin_memcpy(&u.y, &hbt, 4);
    return u;
}

__global__ __launch_bounds__(128) void seg_blend_kernel(
    const float4* __restrict__ pP, const float4* __restrict__ pQ,
    const float* __restrict__ pC, uint2* __restrict__ segbuf) {
    // record: 8 floats (32B): [mx, my, iaF, ib|ic][lop, cr|cg, cb, pad]
    __shared__ __align__(16) float sG[2][2][CHK*8];   // [wave][buf][..]
    const int tid  = threadIdx.x;
    const int lane = tid & 63;
    const int wid  = tid >> 6;                    // 0..1
    const int tile = blockIdx.x & 1023;
    const int seg  = ((int)blockIdx.x >> 10) * 2 + wid;   // 0..7
    const int tX = tile & 31, tY = tile >> 5;
    const int px = tX*16 + (lane & 15);
    const int py = tY*16 + (lane >> 4);           // rows 0..3 (+4k below)
    const float fx = px + 0.5f, fy = py + 0.5f;
    const float x0 = tX*16 + 0.5f, x1 = x0 + 15.0f;
    const float y0 = tY*16 + 0.5f, y1 = y0 + 15.0f;
    const uint64_t lm = (1ull << lane) - 1ull;
    float T0=1.f,T1=1.f,T2=1.f,T3=1.f;
    float aR0=0.f,aG0=0.f,aB0=0.f;
    float aR1=0.f,aG1=0.f,aB1=0.f;
    float aR2=0.f,aG2=0.f,aB2=0.f;
    float aR3=0.f,aG3=0.f,aB3=0.f;
    const int gb = seg * SEGG;

    float4 a0 = pP[gb+lane],    q0 = pQ[gb+lane];    float c0f = pC[gb+lane];
    float4 a1 = pP[gb+64+lane], q1 = pQ[gb+64+lane]; float c1f = pC[gb+64+lane];
    int cntA = 0, cntB = 0;
    // stage chunk 0 -> buf 0 (this wave's private region)
    {
        float nx = fabsf(fminf(fmaxf(a0.x,x0),x1)-a0.x);
        float ny = fabsf(fminf(fmaxf(a0.y,y0),y1)-a0.y);
        bool f0 = (nx <= a0.z) & (ny <= a0.w);
        nx = fabsf(fminf(fmaxf(a1.x,x0),x1)-a1.x);
        ny = fabsf(fminf(fmaxf(a1.y,y0),y1)-a1.y);
        bool f1 = (nx <= a1.z) & (ny <= a1.w);
        uint64_t m0 = __ballot(f0);
        if (f0) { float* rec = &sG[wid][0][__popcll(m0 & lm)*8];
                  *(float4*)rec = make_float4(a0.x,a0.y,q0.x,q0.y);
                  *(float4*)(rec+4) = make_float4(q0.z,q0.w,c0f,0.f); }
        int c0 = (int)__popcll(m0);
        uint64_t m1 = __ballot(f1);
        if (f1) { float* rec = &sG[wid][0][(c0 + __popcll(m1 & lm))*8];
                  *(float4*)rec = make_float4(a1.x,a1.y,q1.x,q1.y);
                  *(float4*)(rec+4) = make_float4(q1.z,q1.w,c1f,0.f); }
        cntA = c0 + (int)__popcll(m1);
    }
    {   const int g = gb + CHK + lane;
        a0 = pP[g]; q0 = pQ[g]; c0f = pC[g];
        a1 = pP[g+64]; q1 = pQ[g+64]; c1f = pC[g+64]; }

    int cur = 0;
    for (int k = 0; k < NCHK; ++k) {
        const int nxt = cur ^ 1;
        if (k + 1 < NCHK) {
            // stage chunk k+1 into this wave's buf[nxt] (single-wave region:
            // program order + lgkmcnt give all fencing needed)
            float nx = fabsf(fminf(fmaxf(a0.x,x0),x1)-a0.x);
            float ny = fabsf(fminf(fmaxf(a0.y,y0),y1)-a0.y);
            bool f0 = (nx <= a0.z) & (ny <= a0.w);
            nx = fabsf(fminf(fmaxf(a1.x,x0),x1)-a1.x);
            ny = fabsf(fminf(fmaxf(a1.y,y0),y1)-a1.y);
            bool f1 = (nx <= a1.z) & (ny <= a1.w);
            uint64_t m0 = __ballot(f0);
            if (f0) { float* rec = &sG[wid][nxt][__popcll(m0 & lm)*8];
                      *(float4*)rec = make_float4(a0.x,a0.y,q0.x,q0.y);
                      *(float4*)(rec+4) = make_float4(q0.z,q0.w,c0f,0.f); }
            int c0 = (int)__popcll(m0);
            uint64_t m1 = __ballot(f1);
            if (f1) { float* rec = &sG[wid][nxt][(c0 + __popcll(m1 & lm))*8];
                      *(float4*)rec = make_float4(a1.x,a1.y,q1.x,q1.y);
                      *(float4*)(rec+4) = make_float4(q1.z,q1.w,c1f,0.f); }
            const int cn = c0 + (int)__popcll(m1);
            if (nxt == 0) cntA = cn; else cntB = cn;
            if (k + 2 < NCHK) {
                const int g = gb + (k+2)*CHK + lane;
                a0 = pP[g]; q0 = pQ[g]; c0f = pC[g];
                a1 = pP[g+64]; q1 = pQ[g+64]; c1f = pC[g+64];
            }
        }
        const int cnt = (cur == 0) ? cntA : cntB;
        const float* segp = sG[wid][cur];
#pragma unroll 2
        for (int i = 0; i < cnt; ++i) {
            const float4 r0 = *(const float4*)(segp + i*8);      // b128
            const float4 r1 = *(const float4*)(segp + i*8 + 4);  // b128
            float dx = fx - r0.x;
            float dy = fy - r0.y;
            unsigned hh = __float_as_uint(r0.w);
            __half2 h2; __builtin_memcpy(&h2, &hh, 4);
            float ibv = __half2float(h2.x);
            float icv = __half2float(h2.y);
            // direct per-row evaluation (round-8-proven math, lop folded in)
            float bse = fmaf(r0.z, dx*dx, r1.x);     // iaF*dx^2 + lop
            float pb  = ibv * dx;                    // ibF*dx (shared by 4 rows)
            float d1 = dy + 4.0f, d2 = dy + 8.0f, d3 = dy + 12.0f;
            float p0 = fmaf(icv, dy*dy, fmaf(pb, dy, bse));
            float p1 = fmaf(icv, d1*d1, fmaf(pb, d1, bse));
            float p2 = fmaf(icv, d2*d2, fmaf(pb, d2, bse));
            float p3 = fmaf(icv, d3*d3, fmaf(pb, d3, bse));
            float al0 = fminf(ALPHA_MAX_C, exp2f(p0));
            float al1 = fminf(ALPHA_MAX_C, exp2f(p1));
            float al2 = fminf(ALPHA_MAX_C, exp2f(p2));
            float al3 = fminf(ALPHA_MAX_C, exp2f(p3));
            al0 = (al0 >= ALPHA_MIN_C) ? al0 : 0.0f;
            al1 = (al1 >= ALPHA_MIN_C) ? al1 : 0.0f;
            al2 = (al2 >= ALPHA_MIN_C) ? al2 : 0.0f;
            al3 = (al3 >= ALPHA_MIN_C) ? al3 : 0.0f;
            if (__any((al0 > 0.f) | (al1 > 0.f) | (al2 > 0.f) | (al3 > 0.f))) {
                unsigned cu = __float_as_uint(r1.y);
                __half2 ch; __builtin_memcpy(&ch, &cu, 4);
                float cr = __half2float(ch.x);
                float cg = __half2float(ch.y);
                float cb = r1.z;
                float s0 = al0*T0, s1 = al1*T1, s2 = al2*T2, s3 = al3*T3;
                aR0 = fmaf(cr,s0,aR0); aG0 = fmaf(cg,s0,aG0); aB0 = fmaf(cb,s0,aB0);
                aR1 = fmaf(cr,s1,aR1); aG1 = fmaf(cg,s1,aG1); aB1 = fmaf(cb,s1,aB1);
                aR2 = fmaf(cr,s2,aR2); aG2 = fmaf(cg,s2,aG2); aB2 = fmaf(cb,s2,aB2);
                aR3 = fmaf(cr,s3,aR3); aG3 = fmaf(cg,s3,aG3); aB3 = fmaf(cb,s3,aB3);
                T0 = fmaf(-al0,T0,T0); T1 = fmaf(-al1,T1,T1);
                T2 = fmaf(-al2,T2,T2); T3 = fmaf(-al3,T3,T3);
            }
        }
        // local early exit: remaining contribution of this segment < eps
        if (__all((T0 < TERM_EPS) & (T1 < TERM_EPS) &
                  (T2 < TERM_EPS) & (T3 < TERM_EPS))) break;
        cur = nxt;
    }
    const int pix0 = py*WW + px;
    uint2* sb = segbuf + seg * NPIX;
    sb[pix0        ] = packAT(aR0, aG0, aB0, T0);
    sb[pix0 +  4*WW] = packAT(aR1, aG1, aB1, T1);
    sb[pix0 +  8*WW] = packAT(aR2, aG2, aB2, T2);
    sb[pix0 + 12*WW] = packAT(aR3, aG3, aB3, T3);
}

// ---------------- Kernel 4: composite segments front-to-back ------------------
__global__ __launch_bounds__(256) void composite_kernel(
    const uint2* __restrict__ segbuf, const float* __restrict__ bg,
    float* __restrict__ out) {
    const int pix = blockIdx.x * 256 + threadIdx.x;
    float R = 0.f, G = 0.f, B = 0.f, T = 1.f;
#pragma unroll
    for (int s = 0; s < NSEG; ++s) {
        uint2 v = segbuf[s * NPIX + pix];
        __half2 hrg, hbt;
        __builtin_memcpy(&hrg, &v.x, 4);
        __builtin_memcpy(&hbt, &v.y, 4);
        R = fmaf(T, __half2float(hrg.x), R);
        G = fmaf(T, __half2float(hrg.y), G);
        B = fmaf(T, __half2float(hbt.x), B);
        T *= __half2float(hbt.y);
    }
    out[pix]          = R + bg[0]*T;
    out[pix +   NPIX] = G + bg[1]*T;
    out[pix + 2*NPIX] = B + bg[2]*T;
}

extern "C" void kernel_launch(void* const* d_in, const int* in_sizes, int n_in,
                              void* d_out, int out_size, void* d_ws, size_t ws_size,
                              hipStream_t stream) {
    const float* means   = (const float*)d_in[0];
    const float* colors  = (const float*)d_in[1];
    const float* ops     = (const float*)d_in[2];
    const float* scales  = (const float*)d_in[3];
    const float* rots    = (const float*)d_in[4];
    const float* depths  = (const float*)d_in[5];
    const float* bg      = (const float*)d_in[6];
    const int N = in_sizes[0] / 2;           // 8192

    char* ws = (char*)d_ws;
    float4* pP    = (float4*)(ws);                        // N*16 B
    float4* pQ    = (float4*)(ws + (size_t)N*16);         // N*16 B
    float*  pC    = (float*) (ws + (size_t)N*32);         // N*4  B
    int*    part  = (int*)  (ws + (size_t)N*36);          // 16*N*4 B
    uint2*  segb  = (uint2*)(ws + (size_t)N*36 + (size_t)16*N*4);  // 16 MB

    const int ngb = N / 256;                 // 32
    const int njb = N / JSL;                 // 16
    rank_kernel<<<dim3(ngb*njb), dim3(256), 0, stream>>>(depths, N, part);
    prep_kernel<<<dim3((N+255)/256), dim3(256), 0, stream>>>(
        means, colors, ops, scales, rots, part, N, pP, pQ, pC);
    seg_blend_kernel<<<dim3(4*1024), dim3(128), 0, stream>>>(pP, pQ, pC, segb);
    composite_kernel<<<dim3(NPIX/256), dim3(256), 0, stream>>>(
        segb, bg, (float*)d_out);
}